// Round 19
// baseline (1059.041 us; speedup 1.0000x reference)
//
#include <hip/hip_runtime.h>

#define U_N 100000
#define I_N 50000
#define D_N 64
#define B_N 4
#define E_N 2000000

#define EDGES   (B_N * E_N)            // 8,000,000 edge-entries per side
#define NSC_U   (U_N / 8)              // 12,500 chunks (8 rows x 4 behaviors)
#define NSC_I   (I_N / 8)              // 6,250 item chunks
#define CROW    12500                  // chunk-row length (even)
#define NBLK    512                    // partition blocks (64 per XCD)
#define EPB     (EDGES / NBLK)         // 15,625 entries per block (exact)
#define CAP     1536                   // fused-kernel LDS sort capacity
#define SC_T    13                     // 1024*13 >= 12,500

// Bin key: bin = row*4 + behavior -> chunk = row>>3, local = ((k&7)<<2)|b.
// ALGEBRA: y = sum v*(emb@W) -> precompute embW (f32; tables L3-resident,
// f32 kills the 4 unpack VALU-ops/entry in fused), no transform stage.
// pay = uint2 { local(5b)<<17 | src(17b), v(f32) } — ONE store per entry
// (write traffic ~ scattered-store count x ~32B; never split the payload).
// NBLK=512 -> 2 blocks/CU in cplace/bhist (r18 ran 1 block/CU = 50% cap).

// ---------------------------------------------------------------------------
// Pass 0: embW = emb @ W (f32). 256 thr, W staged in LDS once, 32 rows/block.
// ---------------------------------------------------------------------------
__global__ __launch_bounds__(256) void precompW_kernel(
        const float* __restrict__ emb, const float* __restrict__ W,
        float* __restrict__ outW, int nrows) {
    __shared__ float Wl[4096];           // 16 KB
    __shared__ float xs[4][64];
    int t = threadIdx.x, w = t >> 6, lane = t & 63;
    for (int i = t; i < 4096; i += 256) Wl[i] = W[i];
    int base = blockIdx.x * 32;
#pragma unroll
    for (int it = 0; it < 8; ++it) {
        int row = base + it * 4 + w;
        __syncthreads();                 // covers Wl (it=0) and xs reuse
        xs[w][lane] = (row < nrows) ? emb[row * 64 + lane] : 0.f;
        __syncthreads();
        if (row < nrows) {
            float y = 0.f;
#pragma unroll 8
            for (int d = 0; d < 64; ++d)
                y = fmaf(xs[w][d], Wl[d * 64 + lane], y);
            outW[row * 64 + lane] = y;
        }
    }
}

// ---------------------------------------------------------------------------
// Pass 1: per-(block, chunk) histogram, packed 2xu16 LDS (25 KB, 2 blk/CU).
// ---------------------------------------------------------------------------
__global__ __launch_bounds__(1024) void bhist_kernel(const int* __restrict__ keys,
                                                     unsigned short* __restrict__ cnt16) {
    __shared__ unsigned h[CROW / 2];
    for (int i = threadIdx.x; i < CROW / 2; i += 1024) h[i] = 0;
    __syncthreads();
    int lb = ((blockIdx.x & 7) << 6) | (blockIdx.x >> 3);   // XCD-major
    int base = lb * EPB;
    for (int i = threadIdx.x; i < EPB; i += 1024) {
        int rc = keys[base + i] >> 3;
        atomicAdd(&h[rc >> 1], 1u << ((rc & 1) * 16));
    }
    __syncthreads();
    unsigned short* row = cnt16 + (size_t)lb * CROW;
    for (int i = threadIdx.x; i < CROW / 2; i += 1024) {
        unsigned v = h[i];
        row[2 * i]     = (unsigned short)(v & 0xFFFFu);
        row[2 * i + 1] = (unsigned short)(v >> 16);
    }
}

// ---------------------------------------------------------------------------
// Pass 2: totals (sum u16 over 512 rows), exclusive scan, then convert the
// count matrix IN PLACE to per-block local prefixes (saves the cur16 array).
// ---------------------------------------------------------------------------
__global__ __launch_bounds__(1024) void scan_tot(const unsigned short* __restrict__ cnt16,
                                                 int nsc, int* __restrict__ cnt_ch) {
    int c = blockIdx.x * 1024 + threadIdx.x;
    if (c >= nsc) return;
    int s = 0;
    for (int lb = 0; lb < NBLK; ++lb) s += cnt16[(size_t)lb * CROW + c];
    cnt_ch[c] = s;
}

__global__ __launch_bounds__(1024) void scan_ex(const int* __restrict__ cnt_ch,
                                                int nsc, int* __restrict__ off_ch) {
    int t = threadIdx.x;
    int loc[SC_T]; int s = 0;
#pragma unroll
    for (int j = 0; j < SC_T; ++j) {
        int idx = t * SC_T + j;
        int c = (idx < nsc) ? cnt_ch[idx] : 0;
        loc[j] = s; s += c;
    }
    __shared__ int sm[1024];
    int mine = s; sm[t] = s; __syncthreads();
    for (int o = 1; o < 1024; o <<= 1) {
        int a = (t >= o) ? sm[t - o] : 0;
        __syncthreads(); sm[t] += a; __syncthreads();
    }
    int pre = sm[t] - mine;
#pragma unroll
    for (int j = 0; j < SC_T; ++j) {
        int idx = t * SC_T + j;
        if (idx < nsc) off_ch[idx] = pre + loc[j];
    }
}

__global__ __launch_bounds__(1024) void scan_cur(unsigned short* __restrict__ cnt16,
                                                 int nsc) {
    int c = blockIdx.x * 1024 + threadIdx.x;
    if (c >= nsc) return;
    int run = 0;
    for (int lb = 0; lb < NBLK; ++lb) {
        int v = cnt16[(size_t)lb * CROW + c];
        cnt16[(size_t)lb * CROW + c] = (unsigned short)run;   // local prefix
        run += v;
    }
}

// ---------------------------------------------------------------------------
// Pass 3: placement. Single pass, ONE uint2 store per entry, zero global
// atomics. NBLK=512 x 1024 thr, 50 KB cursors -> 2 blocks/CU.
// ---------------------------------------------------------------------------
__global__ __launch_bounds__(1024) void cplace_kernel(const int* __restrict__ keys,
                                                      const int* __restrict__ srcs,
                                                      const float* __restrict__ vals,
                                                      const int* __restrict__ off_ch,
                                                      const unsigned short* __restrict__ pre16,
                                                      int nsc,
                                                      uint2* __restrict__ pay) {
    __shared__ int cur[CROW];            // 50 KB
    int lb = ((blockIdx.x & 7) << 6) | (blockIdx.x >> 3);
    const unsigned short* crow = pre16 + (size_t)lb * CROW;
    for (int i = threadIdx.x; i < nsc; i += 1024)
        cur[i] = off_ch[i] + (int)crow[i];
    __syncthreads();
    int base = lb * EPB;
    int b = lb >> 7;                     // behavior: 128 blocks per behavior
    for (int i = threadIdx.x; i < EPB; i += 1024) {
        int gi = base + i;
        int k = keys[gi];
        float v = vals[gi];
        int src = srcs[gi];
        int pos = atomicAdd(&cur[k >> 3], 1);
        pay[pos] = make_uint2(((unsigned)(((k & 7) << 2) | b) << 17) | (unsigned)src,
                              __float_as_uint(v));
    }
}

// ---------------------------------------------------------------------------
// Pass 4 (fused): LDS counting-sort -> quad-row register accumulate of y
// from f32 embW (dwordx4 gather, no unpack) -> quarter-reduce -> sigmoid ->
// float4 stores.
// ---------------------------------------------------------------------------
__global__ __launch_bounds__(512) void fused_kernel(
        const float* __restrict__ embW,
        const int* __restrict__ off_ch,
        const int* __restrict__ cnt_ch,
        const uint2* __restrict__ pay,
        float* __restrict__ embs,        // [B][nrows][64] <- sigmoid(y)
        float* __restrict__ mean_out,    // [nrows][64]    <- sigmoid(mean y)
        int nrows) {
    int g = blockIdx.x;
    int start = off_ch[g], n = cnt_ch[g];
    int t = threadIdx.x, w = t >> 6, lane = t & 63;

    __shared__ uint2 st2[CAP];           // 12.3 KB sorted payload
    __shared__ int c32[32];
    __shared__ int bstart[33];
    float* ys = (float*)st2;             // fallback alias

    if (n <= CAP) {
        if (t < 32) c32[t] = 0;
        __syncthreads();
        for (int i = t; i < n; i += 512)
            atomicAdd(&c32[pay[start + i].x >> 17], 1);
        __syncthreads();
        if (t == 0) {
            int s = 0;
            for (int b2 = 0; b2 < 32; ++b2) {
                bstart[b2] = s; s += c32[b2]; c32[b2] = bstart[b2];
            }
            bstart[32] = s;
        }
        __syncthreads();
        for (int i = t; i < n; i += 512) {
            uint2 p = pay[start + i];
            int pos = atomicAdd(&c32[p.x >> 17], 1);
            st2[pos] = p;
        }
        __syncthreads();

        int qt = lane >> 4, ql = lane & 15;
        float4 a0, a1, a2, a3;
#define ACC_BIN(AQ, Q)                                                        \
        {                                                                     \
            int s0 = bstart[w * 4 + (Q)], s1 = bstart[w * 4 + (Q) + 1];       \
            AQ = make_float4(0.f, 0.f, 0.f, 0.f);                             \
            for (int j = s0; j < s1; j += 4) {                                \
                int idx = j + qt;                                             \
                int jj = idx < s1 ? idx : s1 - 1;                             \
                uint2 p = st2[jj];                                            \
                float v = (idx < s1) ? __uint_as_float(p.y) : 0.f;            \
                float4 x = *((const float4*)(embW +                           \
                              (size_t)(p.x & 0x1FFFFu) * 64) + ql);           \
                AQ.x = fmaf(v, x.x, AQ.x);                                    \
                AQ.y = fmaf(v, x.y, AQ.y);                                    \
                AQ.z = fmaf(v, x.z, AQ.z);                                    \
                AQ.w = fmaf(v, x.w, AQ.w);                                    \
            }                                                                 \
            AQ.x += __shfl_xor(AQ.x, 16); AQ.x += __shfl_xor(AQ.x, 32);       \
            AQ.y += __shfl_xor(AQ.y, 16); AQ.y += __shfl_xor(AQ.y, 32);       \
            AQ.z += __shfl_xor(AQ.z, 16); AQ.z += __shfl_xor(AQ.z, 32);       \
            AQ.w += __shfl_xor(AQ.w, 16); AQ.w += __shfl_xor(AQ.w, 32);       \
        }
        ACC_BIN(a0, 0)
        ACC_BIN(a1, 1)
        ACC_BIN(a2, 2)
        ACC_BIN(a3, 3)
#undef ACC_BIN
        if (qt == 0) {
            int row = g * 8 + w;
            float4 yq[4] = {a0, a1, a2, a3};
#pragma unroll
            for (int q = 0; q < 4; ++q) {
                float4 s4;
                s4.x = 1.f / (1.f + __expf(-yq[q].x));
                s4.y = 1.f / (1.f + __expf(-yq[q].y));
                s4.z = 1.f / (1.f + __expf(-yq[q].z));
                s4.w = 1.f / (1.f + __expf(-yq[q].w));
                *(float4*)&embs[((long long)q * nrows + row) * 64 + 4 * ql] = s4;
            }
            float4 m4;
            m4.x = 0.25f * (a0.x + a1.x + a2.x + a3.x);
            m4.y = 0.25f * (a0.y + a1.y + a2.y + a3.y);
            m4.z = 0.25f * (a0.z + a1.z + a2.z + a3.z);
            m4.w = 0.25f * (a0.w + a1.w + a2.w + a3.w);
            m4.x = 1.f / (1.f + __expf(-m4.x));
            m4.y = 1.f / (1.f + __expf(-m4.y));
            m4.z = 1.f / (1.f + __expf(-m4.z));
            m4.w = 1.f / (1.f + __expf(-m4.w));
            *(float4*)&mean_out[(long long)row * 64 + 4 * ql] = m4;
        }
    } else {
        // Fallback (never for this input): LDS-atomic y accumulate.
        for (int i = t; i < 2048; i += 512) ys[i] = 0.f;
        __syncthreads();
        for (int j = w; j < n; j += 8) {
            uint2 pv = pay[start + j];
            float x = embW[(size_t)(pv.x & 0x1FFFFu) * 64 + lane];
            atomicAdd(&ys[(pv.x >> 17) * 64 + lane],
                      __uint_as_float(pv.y) * x);
        }
        __syncthreads();
        int row = g * 8 + w;
        float y[4];
#pragma unroll
        for (int q = 0; q < 4; ++q) {
            y[q] = ys[(w * 4 + q) * 64 + lane];
            embs[((long long)q * nrows + row) * 64 + lane] =
                1.f / (1.f + __expf(-y[q]));
        }
        float m = 0.25f * (y[0] + y[1] + y[2] + y[3]);
        mean_out[(long long)row * 64 + lane] = 1.f / (1.f + __expf(-m));
    }
}

// ---------------------------------------------------------------------------
// Deep fallback: atomic scatter + separate transform (only if ws too small).
// ---------------------------------------------------------------------------
__global__ void scatter_atomic_kernel(const float* __restrict__ user_emb,
                                      const float* __restrict__ item_emb,
                                      const int* __restrict__ rows,
                                      const int* __restrict__ cols,
                                      const float* __restrict__ vals,
                                      float* __restrict__ stack_u,
                                      float* __restrict__ stack_i) {
    long long tid = (long long)blockIdx.x * blockDim.x + threadIdx.x;
    long long e  = tid >> 4;
    int lane = (int)(tid & 15);
    if (e >= (long long)EDGES) return;
    int b = (int)(e / E_N);
    int r = rows[e];
    int c = cols[e];
    float v = vals[e];
    const float4* irow = (const float4*)(item_emb + (long long)c * D_N);
    const float4* urow = (const float4*)(user_emb + (long long)r * D_N);
    float4 iv = irow[lane];
    float4 uv = urow[lane];
    float* du = stack_u + ((long long)b * U_N + r) * D_N + lane * 4;
    float* di = stack_i + ((long long)b * I_N + c) * D_N + lane * 4;
    atomicAdd(du + 0, v * iv.x);
    atomicAdd(du + 1, v * iv.y);
    atomicAdd(du + 2, v * iv.z);
    atomicAdd(du + 3, v * iv.w);
    atomicAdd(di + 0, v * uv.x);
    atomicAdd(di + 1, v * uv.y);
    atomicAdd(di + 2, v * uv.z);
    atomicAdd(di + 3, v * uv.w);
}

template <int NROWS>
__global__ __launch_bounds__(64) void transform_kernel(
        float* __restrict__ stack,
        const float* __restrict__ W,
        float* __restrict__ mean_out) {
    const int row = blockIdx.x;
    const int j   = threadIdx.x;
    __shared__ float xs[B_N][D_N];
#pragma unroll
    for (int b = 0; b < B_N; ++b)
        xs[b][j] = stack[((long long)b * NROWS + row) * D_N + j];
    __syncthreads();
    float acc[B_N] = {0.f, 0.f, 0.f, 0.f};
#pragma unroll 8
    for (int d = 0; d < D_N; ++d) {
        float w = W[d * D_N + j];
#pragma unroll
        for (int b = 0; b < B_N; ++b)
            acc[b] += xs[b][d] * w;
    }
    float m = 0.25f * (acc[0] + acc[1] + acc[2] + acc[3]);
#pragma unroll
    for (int b = 0; b < B_N; ++b)
        stack[((long long)b * NROWS + row) * D_N + j] =
            1.0f / (1.0f + __expf(-acc[b]));
    mean_out[(long long)row * D_N + j] = 1.0f / (1.0f + __expf(-m));
}

// ---------------------------------------------------------------------------
extern "C" void kernel_launch(void* const* d_in, const int* in_sizes, int n_in,
                              void* d_out, int out_size, void* d_ws, size_t ws_size,
                              hipStream_t stream) {
    const float* user_emb = (const float*)d_in[0];
    const float* item_emb = (const float*)d_in[1];
    const int*   rows     = (const int*)  d_in[2];
    const int*   cols     = (const int*)  d_in[3];
    const float* vals     = (const float*)d_in[4];
    const float* u_w      = (const float*)d_in[5];
    const float* i_w      = (const float*)d_in[6];

    float* out = (float*)d_out;
    float* user_mean = out;
    float* item_mean = out + (long long)U_N * D_N;
    float* stack_u   = item_mean + (long long)I_N * D_N;     // user_embs out
    float* stack_i   = stack_u + (long long)B_N * U_N * D_N; // item_embs out

    // Workspace (~115.3 MB, proven >=128.2 MB in round 4): pay(64) |
    // userWf(25.6) | itemWf(12.8) | cnt16(12.8, doubles as local prefixes) |
    // cnt_ch | off_ch
    uint2* pay = (uint2*)d_ws;
    float* userWf = (float*)(pay + EDGES);                  // user_emb @ i_w
    float* itemWf = userWf + (size_t)U_N * D_N;             // item_emb @ u_w
    unsigned short* cnt16 = (unsigned short*)(itemWf + (size_t)I_N * D_N);
    int* cnt_ch = (int*)(cnt16 + (size_t)NBLK * CROW);
    int* off_ch = cnt_ch + CROW;
    size_t needed = ((char*)(off_ch + CROW)) - (char*)d_ws;

    if (ws_size >= needed) {
        precompW_kernel<<<(I_N + 31) / 32, 256, 0, stream>>>(item_emb, u_w,
                                                             itemWf, I_N);
        precompW_kernel<<<(U_N + 31) / 32, 256, 0, stream>>>(user_emb, i_w,
                                                             userWf, U_N);
        // ---- user side: keys=rows, gathers itemWf ----
        bhist_kernel<<<NBLK, 1024, 0, stream>>>(rows, cnt16);
        scan_tot<<<(NSC_U + 1023) / 1024, 1024, 0, stream>>>(cnt16, NSC_U, cnt_ch);
        scan_ex<<<1, 1024, 0, stream>>>(cnt_ch, NSC_U, off_ch);
        scan_cur<<<(NSC_U + 1023) / 1024, 1024, 0, stream>>>(cnt16, NSC_U);
        cplace_kernel<<<NBLK, 1024, 0, stream>>>(rows, cols, vals, off_ch, cnt16,
                                                 NSC_U, pay);
        fused_kernel<<<NSC_U, 512, 0, stream>>>(itemWf, off_ch, cnt_ch, pay,
                                                stack_u, user_mean, U_N);
        // ---- item side: keys=cols, gathers userWf ----
        bhist_kernel<<<NBLK, 1024, 0, stream>>>(cols, cnt16);
        scan_tot<<<(NSC_I + 1023) / 1024, 1024, 0, stream>>>(cnt16, NSC_I, cnt_ch);
        scan_ex<<<1, 1024, 0, stream>>>(cnt_ch, NSC_I, off_ch);
        scan_cur<<<(NSC_I + 1023) / 1024, 1024, 0, stream>>>(cnt16, NSC_I);
        cplace_kernel<<<NBLK, 1024, 0, stream>>>(cols, rows, vals, off_ch, cnt16,
                                                 NSC_I, pay);
        fused_kernel<<<NSC_I, 512, 0, stream>>>(userWf, off_ch, cnt_ch, pay,
                                                stack_i, item_mean, I_N);
    } else {
        size_t stack_bytes = sizeof(float) * (size_t)B_N * (U_N + I_N) * D_N;
        hipMemsetAsync(stack_u, 0, stack_bytes, stream);
        long long nthreads = (long long)EDGES * 16;
        int nblocks = (int)((nthreads + 255) / 256);
        scatter_atomic_kernel<<<nblocks, 256, 0, stream>>>(
            user_emb, item_emb, rows, cols, vals, stack_u, stack_i);
        transform_kernel<U_N><<<U_N, 64, 0, stream>>>(stack_u, u_w, user_mean);
        transform_kernel<I_N><<<I_N, 64, 0, stream>>>(stack_i, i_w, item_mean);
    }
}

// Round 20
// 930.395 us; speedup vs baseline: 1.1383x; 1.1383x over previous
//
#include <hip/hip_runtime.h>

#define U_N 100000
#define I_N 50000
#define D_N 64
#define B_N 4
#define E_N 2000000

#define EDGES   (B_N * E_N)            // 8,000,000 edge-entries per side
#define NSC_U   (U_N / 8)              // 12,500 chunks (8 rows x 4 behaviors)
#define NSC_I   (I_N / 8)              // 6,250 item chunks
#define CROW    12500                  // chunk-row length (even)
#define NBLK    512                    // partition blocks (64 per XCD)
#define EPB     (EDGES / NBLK)         // 15,625 entries per block (exact)
#define CAP     1536                   // fused-kernel LDS sort capacity
#define SC_T    13                     // 1024*13 >= 12,500

// Bin key: bin = row*4 + behavior -> chunk = row>>3, local = ((k&7)<<2)|b.
// ALGEBRA: y = sum v*(emb@W) -> precompute embW in BF16 (r19 proved f32
// tables blow past per-XCD L2: FETCH 278->880 MB, fused +32%), no transform.
// pay = uint2 { local(5b)<<17 | src(17b), v(f32) } — ONE store per entry
// (write traffic ~ scattered-store count x ~32B; never split the payload).
// NBLK=512 -> 2 blocks/CU in cplace/bhist (store rate scales w/ occupancy).

// ---------------------------------------------------------------------------
// Pass 0: embW = emb @ W -> bf16 (RNE). 256 thr, W staged in LDS once.
// ---------------------------------------------------------------------------
__global__ __launch_bounds__(256) void precompW_kernel(
        const float* __restrict__ emb, const float* __restrict__ W,
        unsigned short* __restrict__ out16, int nrows) {
    __shared__ float Wl[4096];           // 16 KB
    __shared__ float xs[4][64];
    int t = threadIdx.x, w = t >> 6, lane = t & 63;
    for (int i = t; i < 4096; i += 256) Wl[i] = W[i];
    int base = blockIdx.x * 32;
#pragma unroll
    for (int it = 0; it < 8; ++it) {
        int row = base + it * 4 + w;
        __syncthreads();                 // covers Wl (it=0) and xs reuse
        xs[w][lane] = (row < nrows) ? emb[row * 64 + lane] : 0.f;
        __syncthreads();
        if (row < nrows) {
            float y = 0.f;
#pragma unroll 8
            for (int d = 0; d < 64; ++d)
                y = fmaf(xs[w][d], Wl[d * 64 + lane], y);
            unsigned u = __float_as_uint(y);
            u += 0x7FFFu + ((u >> 16) & 1u);
            out16[row * 64 + lane] = (unsigned short)(u >> 16);
        }
    }
}

// ---------------------------------------------------------------------------
// Pass 1: per-(block, chunk) histogram, packed 2xu16 LDS (25 KB, 2 blk/CU).
// ---------------------------------------------------------------------------
__global__ __launch_bounds__(1024) void bhist_kernel(const int* __restrict__ keys,
                                                     unsigned short* __restrict__ cnt16) {
    __shared__ unsigned h[CROW / 2];
    for (int i = threadIdx.x; i < CROW / 2; i += 1024) h[i] = 0;
    __syncthreads();
    int lb = ((blockIdx.x & 7) << 6) | (blockIdx.x >> 3);   // XCD-major
    int base = lb * EPB;
    for (int i = threadIdx.x; i < EPB; i += 1024) {
        int rc = keys[base + i] >> 3;
        atomicAdd(&h[rc >> 1], 1u << ((rc & 1) * 16));
    }
    __syncthreads();
    unsigned short* row = cnt16 + (size_t)lb * CROW;
    for (int i = threadIdx.x; i < CROW / 2; i += 1024) {
        unsigned v = h[i];
        row[2 * i]     = (unsigned short)(v & 0xFFFFu);
        row[2 * i + 1] = (unsigned short)(v >> 16);
    }
}

// ---------------------------------------------------------------------------
// Pass 2: totals (sum u16 over 512 rows), exclusive scan, then convert the
// count matrix IN PLACE to per-block local prefixes.
// ---------------------------------------------------------------------------
__global__ __launch_bounds__(1024) void scan_tot(const unsigned short* __restrict__ cnt16,
                                                 int nsc, int* __restrict__ cnt_ch) {
    int c = blockIdx.x * 1024 + threadIdx.x;
    if (c >= nsc) return;
    int s = 0;
    for (int lb = 0; lb < NBLK; ++lb) s += cnt16[(size_t)lb * CROW + c];
    cnt_ch[c] = s;
}

__global__ __launch_bounds__(1024) void scan_ex(const int* __restrict__ cnt_ch,
                                                int nsc, int* __restrict__ off_ch) {
    int t = threadIdx.x;
    int loc[SC_T]; int s = 0;
#pragma unroll
    for (int j = 0; j < SC_T; ++j) {
        int idx = t * SC_T + j;
        int c = (idx < nsc) ? cnt_ch[idx] : 0;
        loc[j] = s; s += c;
    }
    __shared__ int sm[1024];
    int mine = s; sm[t] = s; __syncthreads();
    for (int o = 1; o < 1024; o <<= 1) {
        int a = (t >= o) ? sm[t - o] : 0;
        __syncthreads(); sm[t] += a; __syncthreads();
    }
    int pre = sm[t] - mine;
#pragma unroll
    for (int j = 0; j < SC_T; ++j) {
        int idx = t * SC_T + j;
        if (idx < nsc) off_ch[idx] = pre + loc[j];
    }
}

__global__ __launch_bounds__(1024) void scan_cur(unsigned short* __restrict__ cnt16,
                                                 int nsc) {
    int c = blockIdx.x * 1024 + threadIdx.x;
    if (c >= nsc) return;
    int run = 0;
    for (int lb = 0; lb < NBLK; ++lb) {
        int v = cnt16[(size_t)lb * CROW + c];
        cnt16[(size_t)lb * CROW + c] = (unsigned short)run;   // local prefix
        run += v;
    }
}

// ---------------------------------------------------------------------------
// Pass 3: placement. Single pass, ONE uint2 store per entry, zero global
// atomics. NBLK=512 x 1024 thr, 50 KB cursors -> 2 blocks/CU.
// ---------------------------------------------------------------------------
__global__ __launch_bounds__(1024) void cplace_kernel(const int* __restrict__ keys,
                                                      const int* __restrict__ srcs,
                                                      const float* __restrict__ vals,
                                                      const int* __restrict__ off_ch,
                                                      const unsigned short* __restrict__ pre16,
                                                      int nsc,
                                                      uint2* __restrict__ pay) {
    __shared__ int cur[CROW];            // 50 KB
    int lb = ((blockIdx.x & 7) << 6) | (blockIdx.x >> 3);
    const unsigned short* crow = pre16 + (size_t)lb * CROW;
    for (int i = threadIdx.x; i < nsc; i += 1024)
        cur[i] = off_ch[i] + (int)crow[i];
    __syncthreads();
    int base = lb * EPB;
    int b = lb >> 7;                     // behavior: 128 blocks per behavior
    for (int i = threadIdx.x; i < EPB; i += 1024) {
        int gi = base + i;
        int k = keys[gi];
        float v = vals[gi];
        int src = srcs[gi];
        int pos = atomicAdd(&cur[k >> 3], 1);
        pay[pos] = make_uint2(((unsigned)(((k & 7) << 2) | b) << 17) | (unsigned)src,
                              __float_as_uint(v));
    }
}

// ---------------------------------------------------------------------------
// Pass 4 (fused, r18-exact): LDS counting-sort -> quad-row register
// accumulate of y from bf16 embW16 -> quarter-reduce -> sigmoid -> float4.
// ---------------------------------------------------------------------------
__global__ __launch_bounds__(512) void fused_kernel(
        const unsigned short* __restrict__ embW16,
        const int* __restrict__ off_ch,
        const int* __restrict__ cnt_ch,
        const uint2* __restrict__ pay,
        float* __restrict__ embs,        // [B][nrows][64] <- sigmoid(y)
        float* __restrict__ mean_out,    // [nrows][64]    <- sigmoid(mean y)
        int nrows) {
    int g = blockIdx.x;
    int start = off_ch[g], n = cnt_ch[g];
    int t = threadIdx.x, w = t >> 6, lane = t & 63;

    __shared__ uint2 st2[CAP];           // 12.3 KB sorted payload
    __shared__ int c32[32];
    __shared__ int bstart[33];
    float* ys = (float*)st2;             // fallback alias

    if (n <= CAP) {
        if (t < 32) c32[t] = 0;
        __syncthreads();
        for (int i = t; i < n; i += 512)
            atomicAdd(&c32[pay[start + i].x >> 17], 1);
        __syncthreads();
        if (t == 0) {
            int s = 0;
            for (int b2 = 0; b2 < 32; ++b2) {
                bstart[b2] = s; s += c32[b2]; c32[b2] = bstart[b2];
            }
            bstart[32] = s;
        }
        __syncthreads();
        for (int i = t; i < n; i += 512) {
            uint2 p = pay[start + i];
            int pos = atomicAdd(&c32[p.x >> 17], 1);
            st2[pos] = p;
        }
        __syncthreads();

        int qt = lane >> 4, ql = lane & 15;
        float4 a0, a1, a2, a3;
#define ACC_BIN(AQ, Q)                                                        \
        {                                                                     \
            int s0 = bstart[w * 4 + (Q)], s1 = bstart[w * 4 + (Q) + 1];       \
            AQ = make_float4(0.f, 0.f, 0.f, 0.f);                             \
            for (int j = s0; j < s1; j += 4) {                                \
                int idx = j + qt;                                             \
                int jj = idx < s1 ? idx : s1 - 1;                             \
                uint2 p = st2[jj];                                            \
                float v = (idx < s1) ? __uint_as_float(p.y) : 0.f;            \
                uint2 x = *((const uint2*)(embW16 +                           \
                              (size_t)(p.x & 0x1FFFFu) * 64) + ql);           \
                AQ.x = fmaf(v, __uint_as_float(x.x << 16), AQ.x);             \
                AQ.y = fmaf(v, __uint_as_float(x.x & 0xFFFF0000u), AQ.y);     \
                AQ.z = fmaf(v, __uint_as_float(x.y << 16), AQ.z);             \
                AQ.w = fmaf(v, __uint_as_float(x.y & 0xFFFF0000u), AQ.w);     \
            }                                                                 \
            AQ.x += __shfl_xor(AQ.x, 16); AQ.x += __shfl_xor(AQ.x, 32);       \
            AQ.y += __shfl_xor(AQ.y, 16); AQ.y += __shfl_xor(AQ.y, 32);       \
            AQ.z += __shfl_xor(AQ.z, 16); AQ.z += __shfl_xor(AQ.z, 32);       \
            AQ.w += __shfl_xor(AQ.w, 16); AQ.w += __shfl_xor(AQ.w, 32);       \
        }
        ACC_BIN(a0, 0)
        ACC_BIN(a1, 1)
        ACC_BIN(a2, 2)
        ACC_BIN(a3, 3)
#undef ACC_BIN
        if (qt == 0) {
            int row = g * 8 + w;
            float4 yq[4] = {a0, a1, a2, a3};
#pragma unroll
            for (int q = 0; q < 4; ++q) {
                float4 s4;
                s4.x = 1.f / (1.f + __expf(-yq[q].x));
                s4.y = 1.f / (1.f + __expf(-yq[q].y));
                s4.z = 1.f / (1.f + __expf(-yq[q].z));
                s4.w = 1.f / (1.f + __expf(-yq[q].w));
                *(float4*)&embs[((long long)q * nrows + row) * 64 + 4 * ql] = s4;
            }
            float4 m4;
            m4.x = 0.25f * (a0.x + a1.x + a2.x + a3.x);
            m4.y = 0.25f * (a0.y + a1.y + a2.y + a3.y);
            m4.z = 0.25f * (a0.z + a1.z + a2.z + a3.z);
            m4.w = 0.25f * (a0.w + a1.w + a2.w + a3.w);
            m4.x = 1.f / (1.f + __expf(-m4.x));
            m4.y = 1.f / (1.f + __expf(-m4.y));
            m4.z = 1.f / (1.f + __expf(-m4.z));
            m4.w = 1.f / (1.f + __expf(-m4.w));
            *(float4*)&mean_out[(long long)row * 64 + 4 * ql] = m4;
        }
    } else {
        // Fallback (never for this input): LDS-atomic y accumulate.
        for (int i = t; i < 2048; i += 512) ys[i] = 0.f;
        __syncthreads();
        for (int j = w; j < n; j += 8) {
            uint2 pv = pay[start + j];
            float x = __uint_as_float(
                (unsigned)embW16[(size_t)(pv.x & 0x1FFFFu) * 64 + lane] << 16);
            atomicAdd(&ys[(pv.x >> 17) * 64 + lane],
                      __uint_as_float(pv.y) * x);
        }
        __syncthreads();
        int row = g * 8 + w;
        float y[4];
#pragma unroll
        for (int q = 0; q < 4; ++q) {
            y[q] = ys[(w * 4 + q) * 64 + lane];
            embs[((long long)q * nrows + row) * 64 + lane] =
                1.f / (1.f + __expf(-y[q]));
        }
        float m = 0.25f * (y[0] + y[1] + y[2] + y[3]);
        mean_out[(long long)row * 64 + lane] = 1.f / (1.f + __expf(-m));
    }
}

// ---------------------------------------------------------------------------
// Deep fallback: atomic scatter + separate transform (only if ws too small).
// ---------------------------------------------------------------------------
__global__ void scatter_atomic_kernel(const float* __restrict__ user_emb,
                                      const float* __restrict__ item_emb,
                                      const int* __restrict__ rows,
                                      const int* __restrict__ cols,
                                      const float* __restrict__ vals,
                                      float* __restrict__ stack_u,
                                      float* __restrict__ stack_i) {
    long long tid = (long long)blockIdx.x * blockDim.x + threadIdx.x;
    long long e  = tid >> 4;
    int lane = (int)(tid & 15);
    if (e >= (long long)EDGES) return;
    int b = (int)(e / E_N);
    int r = rows[e];
    int c = cols[e];
    float v = vals[e];
    const float4* irow = (const float4*)(item_emb + (long long)c * D_N);
    const float4* urow = (const float4*)(user_emb + (long long)r * D_N);
    float4 iv = irow[lane];
    float4 uv = urow[lane];
    float* du = stack_u + ((long long)b * U_N + r) * D_N + lane * 4;
    float* di = stack_i + ((long long)b * I_N + c) * D_N + lane * 4;
    atomicAdd(du + 0, v * iv.x);
    atomicAdd(du + 1, v * iv.y);
    atomicAdd(du + 2, v * iv.z);
    atomicAdd(du + 3, v * iv.w);
    atomicAdd(di + 0, v * uv.x);
    atomicAdd(di + 1, v * uv.y);
    atomicAdd(di + 2, v * uv.z);
    atomicAdd(di + 3, v * uv.w);
}

template <int NROWS>
__global__ __launch_bounds__(64) void transform_kernel(
        float* __restrict__ stack,
        const float* __restrict__ W,
        float* __restrict__ mean_out) {
    const int row = blockIdx.x;
    const int j   = threadIdx.x;
    __shared__ float xs[B_N][D_N];
#pragma unroll
    for (int b = 0; b < B_N; ++b)
        xs[b][j] = stack[((long long)b * NROWS + row) * D_N + j];
    __syncthreads();
    float acc[B_N] = {0.f, 0.f, 0.f, 0.f};
#pragma unroll 8
    for (int d = 0; d < D_N; ++d) {
        float w = W[d * D_N + j];
#pragma unroll
        for (int b = 0; b < B_N; ++b)
            acc[b] += xs[b][d] * w;
    }
    float m = 0.25f * (acc[0] + acc[1] + acc[2] + acc[3]);
#pragma unroll
    for (int b = 0; b < B_N; ++b)
        stack[((long long)b * NROWS + row) * D_N + j] =
            1.0f / (1.0f + __expf(-acc[b]));
    mean_out[(long long)row * D_N + j] = 1.0f / (1.0f + __expf(-m));
}

// ---------------------------------------------------------------------------
extern "C" void kernel_launch(void* const* d_in, const int* in_sizes, int n_in,
                              void* d_out, int out_size, void* d_ws, size_t ws_size,
                              hipStream_t stream) {
    const float* user_emb = (const float*)d_in[0];
    const float* item_emb = (const float*)d_in[1];
    const int*   rows     = (const int*)  d_in[2];
    const int*   cols     = (const int*)  d_in[3];
    const float* vals     = (const float*)d_in[4];
    const float* u_w      = (const float*)d_in[5];
    const float* i_w      = (const float*)d_in[6];

    float* out = (float*)d_out;
    float* user_mean = out;
    float* item_mean = out + (long long)U_N * D_N;
    float* stack_u   = item_mean + (long long)I_N * D_N;     // user_embs out
    float* stack_i   = stack_u + (long long)B_N * U_N * D_N; // item_embs out

    // Workspace (~96 MB): pay(64) | userW16(12.8) | itemW16(6.4) |
    //                     cnt16(12.8, becomes local prefixes) | cnt_ch | off_ch
    uint2* pay = (uint2*)d_ws;
    unsigned short* userW16 = (unsigned short*)(pay + EDGES);   // user_emb @ i_w
    unsigned short* itemW16 = userW16 + (size_t)U_N * D_N;      // item_emb @ u_w
    unsigned short* cnt16 = itemW16 + (size_t)I_N * D_N;
    int* cnt_ch = (int*)(cnt16 + (size_t)NBLK * CROW);
    int* off_ch = cnt_ch + CROW;
    size_t needed = ((char*)(off_ch + CROW)) - (char*)d_ws;

    if (ws_size >= needed) {
        precompW_kernel<<<(I_N + 31) / 32, 256, 0, stream>>>(item_emb, u_w,
                                                             itemW16, I_N);
        precompW_kernel<<<(U_N + 31) / 32, 256, 0, stream>>>(user_emb, i_w,
                                                             userW16, U_N);
        // ---- user side: keys=rows, gathers itemW16 ----
        bhist_kernel<<<NBLK, 1024, 0, stream>>>(rows, cnt16);
        scan_tot<<<(NSC_U + 1023) / 1024, 1024, 0, stream>>>(cnt16, NSC_U, cnt_ch);
        scan_ex<<<1, 1024, 0, stream>>>(cnt_ch, NSC_U, off_ch);
        scan_cur<<<(NSC_U + 1023) / 1024, 1024, 0, stream>>>(cnt16, NSC_U);
        cplace_kernel<<<NBLK, 1024, 0, stream>>>(rows, cols, vals, off_ch, cnt16,
                                                 NSC_U, pay);
        fused_kernel<<<NSC_U, 512, 0, stream>>>(itemW16, off_ch, cnt_ch, pay,
                                                stack_u, user_mean, U_N);
        // ---- item side: keys=cols, gathers userW16 ----
        bhist_kernel<<<NBLK, 1024, 0, stream>>>(cols, cnt16);
        scan_tot<<<(NSC_I + 1023) / 1024, 1024, 0, stream>>>(cnt16, NSC_I, cnt_ch);
        scan_ex<<<1, 1024, 0, stream>>>(cnt_ch, NSC_I, off_ch);
        scan_cur<<<(NSC_I + 1023) / 1024, 1024, 0, stream>>>(cnt16, NSC_I);
        cplace_kernel<<<NBLK, 1024, 0, stream>>>(cols, rows, vals, off_ch, cnt16,
                                                 NSC_I, pay);
        fused_kernel<<<NSC_I, 512, 0, stream>>>(userW16, off_ch, cnt_ch, pay,
                                                stack_i, item_mean, I_N);
    } else {
        size_t stack_bytes = sizeof(float) * (size_t)B_N * (U_N + I_N) * D_N;
        hipMemsetAsync(stack_u, 0, stack_bytes, stream);
        long long nthreads = (long long)EDGES * 16;
        int nblocks = (int)((nthreads + 255) / 256);
        scatter_atomic_kernel<<<nblocks, 256, 0, stream>>>(
            user_emb, item_emb, rows, cols, vals, stack_u, stack_i);
        transform_kernel<U_N><<<U_N, 64, 0, stream>>>(stack_u, u_w, user_mean);
        transform_kernel<I_N><<<I_N, 64, 0, stream>>>(stack_i, i_w, item_mean);
    }
}

// Round 21
// 896.099 us; speedup vs baseline: 1.1818x; 1.0383x over previous
//
#include <hip/hip_runtime.h>

#define U_N 100000
#define I_N 50000
#define D_N 64
#define B_N 4
#define E_N 2000000

#define EDGES   (B_N * E_N)            // 8,000,000 edge-entries per side
#define NSC_U   (U_N / 8)              // 12,500 chunks (8 rows x 4 behaviors)
#define NSC_I   (I_N / 8)              // 6,250 item chunks
#define CROW    12500                  // chunk-row length (even)
#define NBLK    512                    // partition blocks (64 per XCD)
#define EPB     (EDGES / NBLK)         // 15,625 entries per block (exact)
#define CAP     1536                   // fused-kernel LDS sort capacity
#define SC_T    13                     // 1024*13 >= 12,500

// Bin key: bin = row*4 + behavior -> chunk = row>>3, local = ((k&7)<<2)|b.
// ALGEBRA: y = sum v*(emb@W) -> precompute embW in BF16 (f32 tables blow L2).
// pay = uint2 { local(5b)<<17 | src(17b), v(f32) } — ONE store per entry.
// NT HYPOTHESIS (this round): the residual 4.5x write amp / 3x fetch amp is
// streaming traffic LRU-evicting L2-resident lines (pay frontiers, embW).
// All single-use streams -> nontemporal; write-once outputs -> nontemporal.

typedef unsigned vu2 __attribute__((ext_vector_type(2)));
typedef float    vf4 __attribute__((ext_vector_type(4)));

__device__ __forceinline__ void nt_store4(float* p, float4 v) {
    vf4 x = {v.x, v.y, v.z, v.w};
    __builtin_nontemporal_store(x, (vf4*)p);
}

// ---------------------------------------------------------------------------
// Pass 0: embW = emb @ W -> bf16 (RNE). 256 thr, W staged in LDS once.
// ---------------------------------------------------------------------------
__global__ __launch_bounds__(256) void precompW_kernel(
        const float* __restrict__ emb, const float* __restrict__ W,
        unsigned short* __restrict__ out16, int nrows) {
    __shared__ float Wl[4096];           // 16 KB
    __shared__ float xs[4][64];
    int t = threadIdx.x, w = t >> 6, lane = t & 63;
    for (int i = t; i < 4096; i += 256) Wl[i] = W[i];
    int base = blockIdx.x * 32;
#pragma unroll
    for (int it = 0; it < 8; ++it) {
        int row = base + it * 4 + w;
        __syncthreads();                 // covers Wl (it=0) and xs reuse
        xs[w][lane] = (row < nrows) ? emb[row * 64 + lane] : 0.f;
        __syncthreads();
        if (row < nrows) {
            float y = 0.f;
#pragma unroll 8
            for (int d = 0; d < 64; ++d)
                y = fmaf(xs[w][d], Wl[d * 64 + lane], y);
            unsigned u = __float_as_uint(y);
            u += 0x7FFFu + ((u >> 16) & 1u);
            out16[row * 64 + lane] = (unsigned short)(u >> 16);
        }
    }
}

// ---------------------------------------------------------------------------
// Pass 1: per-(block, chunk) histogram, packed 2xu16 LDS. NT key reads.
// ---------------------------------------------------------------------------
__global__ __launch_bounds__(1024) void bhist_kernel(const int* __restrict__ keys,
                                                     unsigned short* __restrict__ cnt16) {
    __shared__ unsigned h[CROW / 2];
    for (int i = threadIdx.x; i < CROW / 2; i += 1024) h[i] = 0;
    __syncthreads();
    int lb = ((blockIdx.x & 7) << 6) | (blockIdx.x >> 3);   // XCD-major
    int base = lb * EPB;
    for (int i = threadIdx.x; i < EPB; i += 1024) {
        int rc = __builtin_nontemporal_load(&keys[base + i]) >> 3;
        atomicAdd(&h[rc >> 1], 1u << ((rc & 1) * 16));
    }
    __syncthreads();
    unsigned short* row = cnt16 + (size_t)lb * CROW;
    for (int i = threadIdx.x; i < CROW / 2; i += 1024) {
        unsigned v = h[i];
        row[2 * i]     = (unsigned short)(v & 0xFFFFu);
        row[2 * i + 1] = (unsigned short)(v >> 16);
    }
}

// ---------------------------------------------------------------------------
// Pass 2: totals, exclusive scan, counts -> per-block local prefixes in place.
// ---------------------------------------------------------------------------
__global__ __launch_bounds__(1024) void scan_tot(const unsigned short* __restrict__ cnt16,
                                                 int nsc, int* __restrict__ cnt_ch) {
    int c = blockIdx.x * 1024 + threadIdx.x;
    if (c >= nsc) return;
    int s = 0;
    for (int lb = 0; lb < NBLK; ++lb) s += cnt16[(size_t)lb * CROW + c];
    cnt_ch[c] = s;
}

__global__ __launch_bounds__(1024) void scan_ex(const int* __restrict__ cnt_ch,
                                                int nsc, int* __restrict__ off_ch) {
    int t = threadIdx.x;
    int loc[SC_T]; int s = 0;
#pragma unroll
    for (int j = 0; j < SC_T; ++j) {
        int idx = t * SC_T + j;
        int c = (idx < nsc) ? cnt_ch[idx] : 0;
        loc[j] = s; s += c;
    }
    __shared__ int sm[1024];
    int mine = s; sm[t] = s; __syncthreads();
    for (int o = 1; o < 1024; o <<= 1) {
        int a = (t >= o) ? sm[t - o] : 0;
        __syncthreads(); sm[t] += a; __syncthreads();
    }
    int pre = sm[t] - mine;
#pragma unroll
    for (int j = 0; j < SC_T; ++j) {
        int idx = t * SC_T + j;
        if (idx < nsc) off_ch[idx] = pre + loc[j];
    }
}

__global__ __launch_bounds__(1024) void scan_cur(unsigned short* __restrict__ cnt16,
                                                 int nsc) {
    int c = blockIdx.x * 1024 + threadIdx.x;
    if (c >= nsc) return;
    int run = 0;
    for (int lb = 0; lb < NBLK; ++lb) {
        int v = cnt16[(size_t)lb * CROW + c];
        cnt16[(size_t)lb * CROW + c] = (unsigned short)run;   // local prefix
        run += v;
    }
}

// ---------------------------------------------------------------------------
// Pass 3: placement. NT reads of keys/srcs/vals (single-use streams) keep L2
// free for pay write-combining. ONE uint2 store per entry, zero global
// atomics. NBLK=512 x 1024 thr, 50 KB cursors -> 2 blocks/CU.
// ---------------------------------------------------------------------------
__global__ __launch_bounds__(1024) void cplace_kernel(const int* __restrict__ keys,
                                                      const int* __restrict__ srcs,
                                                      const float* __restrict__ vals,
                                                      const int* __restrict__ off_ch,
                                                      const unsigned short* __restrict__ pre16,
                                                      int nsc,
                                                      uint2* __restrict__ pay) {
    __shared__ int cur[CROW];            // 50 KB
    int lb = ((blockIdx.x & 7) << 6) | (blockIdx.x >> 3);
    const unsigned short* crow = pre16 + (size_t)lb * CROW;
    for (int i = threadIdx.x; i < nsc; i += 1024)
        cur[i] = off_ch[i] + (int)crow[i];
    __syncthreads();
    int base = lb * EPB;
    int b = lb >> 7;                     // behavior: 128 blocks per behavior
    for (int i = threadIdx.x; i < EPB; i += 1024) {
        int gi = base + i;
        int k    = __builtin_nontemporal_load(&keys[gi]);
        float v  = __builtin_nontemporal_load(&vals[gi]);
        int src  = __builtin_nontemporal_load(&srcs[gi]);
        int pos = atomicAdd(&cur[k >> 3], 1);
        pay[pos] = make_uint2(((unsigned)(((k & 7) << 2) | b) << 17) | (unsigned)src,
                              __float_as_uint(v));
    }
}

// ---------------------------------------------------------------------------
// Pass 4 (fused): NT-read pay ONCE into LDS staging (count in same pass) ->
// prefix -> LDS scatter -> quad-row register accumulate of y from bf16
// embW16 (embW stays L2-resident now) -> quarter-reduce -> sigmoid -> NT
// float4 stores. LDS ~25 KB -> 4 blocks/CU.
// ---------------------------------------------------------------------------
__global__ __launch_bounds__(512) void fused_kernel(
        const unsigned short* __restrict__ embW16,
        const int* __restrict__ off_ch,
        const int* __restrict__ cnt_ch,
        const uint2* __restrict__ pay,
        float* __restrict__ embs,        // [B][nrows][64] <- sigmoid(y)
        float* __restrict__ mean_out,    // [nrows][64]    <- sigmoid(mean y)
        int nrows) {
    int g = blockIdx.x;
    int start = off_ch[g], n = cnt_ch[g];
    int t = threadIdx.x, w = t >> 6, lane = t & 63;

    __shared__ uint2 st[CAP];            // 12.3 KB staged payload
    __shared__ uint2 st2[CAP];           // 12.3 KB sorted payload
    __shared__ int c32[32];
    __shared__ int bstart[33];
    float* ys = (float*)st2;             // fallback alias

    if (n <= CAP) {
        if (t < 32) c32[t] = 0;
        __syncthreads();
        for (int i = t; i < n; i += 512) {
            vu2 p = __builtin_nontemporal_load((const vu2*)&pay[start + i]);
            st[i] = make_uint2(p.x, p.y);
            atomicAdd(&c32[p.x >> 17], 1);
        }
        __syncthreads();
        if (t == 0) {
            int s = 0;
            for (int b2 = 0; b2 < 32; ++b2) {
                bstart[b2] = s; s += c32[b2]; c32[b2] = bstart[b2];
            }
            bstart[32] = s;
        }
        __syncthreads();
        for (int i = t; i < n; i += 512) {
            uint2 p = st[i];
            int pos = atomicAdd(&c32[p.x >> 17], 1);
            st2[pos] = p;
        }
        __syncthreads();

        int qt = lane >> 4, ql = lane & 15;
        float4 a0, a1, a2, a3;
#define ACC_BIN(AQ, Q)                                                        \
        {                                                                     \
            int s0 = bstart[w * 4 + (Q)], s1 = bstart[w * 4 + (Q) + 1];       \
            AQ = make_float4(0.f, 0.f, 0.f, 0.f);                             \
            for (int j = s0; j < s1; j += 4) {                                \
                int idx = j + qt;                                             \
                int jj = idx < s1 ? idx : s1 - 1;                             \
                uint2 p = st2[jj];                                            \
                float v = (idx < s1) ? __uint_as_float(p.y) : 0.f;            \
                uint2 x = *((const uint2*)(embW16 +                           \
                              (size_t)(p.x & 0x1FFFFu) * 64) + ql);           \
                AQ.x = fmaf(v, __uint_as_float(x.x << 16), AQ.x);             \
                AQ.y = fmaf(v, __uint_as_float(x.x & 0xFFFF0000u), AQ.y);     \
                AQ.z = fmaf(v, __uint_as_float(x.y << 16), AQ.z);             \
                AQ.w = fmaf(v, __uint_as_float(x.y & 0xFFFF0000u), AQ.w);     \
            }                                                                 \
            AQ.x += __shfl_xor(AQ.x, 16); AQ.x += __shfl_xor(AQ.x, 32);       \
            AQ.y += __shfl_xor(AQ.y, 16); AQ.y += __shfl_xor(AQ.y, 32);       \
            AQ.z += __shfl_xor(AQ.z, 16); AQ.z += __shfl_xor(AQ.z, 32);       \
            AQ.w += __shfl_xor(AQ.w, 16); AQ.w += __shfl_xor(AQ.w, 32);       \
        }
        ACC_BIN(a0, 0)
        ACC_BIN(a1, 1)
        ACC_BIN(a2, 2)
        ACC_BIN(a3, 3)
#undef ACC_BIN
        if (qt == 0) {
            int row = g * 8 + w;
            float4 yq[4] = {a0, a1, a2, a3};
#pragma unroll
            for (int q = 0; q < 4; ++q) {
                float4 s4;
                s4.x = 1.f / (1.f + __expf(-yq[q].x));
                s4.y = 1.f / (1.f + __expf(-yq[q].y));
                s4.z = 1.f / (1.f + __expf(-yq[q].z));
                s4.w = 1.f / (1.f + __expf(-yq[q].w));
                nt_store4(&embs[((long long)q * nrows + row) * 64 + 4 * ql], s4);
            }
            float4 m4;
            m4.x = 0.25f * (a0.x + a1.x + a2.x + a3.x);
            m4.y = 0.25f * (a0.y + a1.y + a2.y + a3.y);
            m4.z = 0.25f * (a0.z + a1.z + a2.z + a3.z);
            m4.w = 0.25f * (a0.w + a1.w + a2.w + a3.w);
            m4.x = 1.f / (1.f + __expf(-m4.x));
            m4.y = 1.f / (1.f + __expf(-m4.y));
            m4.z = 1.f / (1.f + __expf(-m4.z));
            m4.w = 1.f / (1.f + __expf(-m4.w));
            nt_store4(&mean_out[(long long)row * 64 + 4 * ql], m4);
        }
    } else {
        // Fallback (never for this input): LDS-atomic y accumulate.
        for (int i = t; i < 2048; i += 512) ys[i] = 0.f;
        __syncthreads();
        for (int j = w; j < n; j += 8) {
            uint2 pv = pay[start + j];
            float x = __uint_as_float(
                (unsigned)embW16[(size_t)(pv.x & 0x1FFFFu) * 64 + lane] << 16);
            atomicAdd(&ys[(pv.x >> 17) * 64 + lane],
                      __uint_as_float(pv.y) * x);
        }
        __syncthreads();
        int row = g * 8 + w;
        float y[4];
#pragma unroll
        for (int q = 0; q < 4; ++q) {
            y[q] = ys[(w * 4 + q) * 64 + lane];
            embs[((long long)q * nrows + row) * 64 + lane] =
                1.f / (1.f + __expf(-y[q]));
        }
        float m = 0.25f * (y[0] + y[1] + y[2] + y[3]);
        mean_out[(long long)row * 64 + lane] = 1.f / (1.f + __expf(-m));
    }
}

// ---------------------------------------------------------------------------
// Deep fallback: atomic scatter + separate transform (only if ws too small).
// ---------------------------------------------------------------------------
__global__ void scatter_atomic_kernel(const float* __restrict__ user_emb,
                                      const float* __restrict__ item_emb,
                                      const int* __restrict__ rows,
                                      const int* __restrict__ cols,
                                      const float* __restrict__ vals,
                                      float* __restrict__ stack_u,
                                      float* __restrict__ stack_i) {
    long long tid = (long long)blockIdx.x * blockDim.x + threadIdx.x;
    long long e  = tid >> 4;
    int lane = (int)(tid & 15);
    if (e >= (long long)EDGES) return;
    int b = (int)(e / E_N);
    int r = rows[e];
    int c = cols[e];
    float v = vals[e];
    const float4* irow = (const float4*)(item_emb + (long long)c * D_N);
    const float4* urow = (const float4*)(user_emb + (long long)r * D_N);
    float4 iv = irow[lane];
    float4 uv = urow[lane];
    float* du = stack_u + ((long long)b * U_N + r) * D_N + lane * 4;
    float* di = stack_i + ((long long)b * I_N + c) * D_N + lane * 4;
    atomicAdd(du + 0, v * iv.x);
    atomicAdd(du + 1, v * iv.y);
    atomicAdd(du + 2, v * iv.z);
    atomicAdd(du + 3, v * iv.w);
    atomicAdd(di + 0, v * uv.x);
    atomicAdd(di + 1, v * uv.y);
    atomicAdd(di + 2, v * uv.z);
    atomicAdd(di + 3, v * uv.w);
}

template <int NROWS>
__global__ __launch_bounds__(64) void transform_kernel(
        float* __restrict__ stack,
        const float* __restrict__ W,
        float* __restrict__ mean_out) {
    const int row = blockIdx.x;
    const int j   = threadIdx.x;
    __shared__ float xs[B_N][D_N];
#pragma unroll
    for (int b = 0; b < B_N; ++b)
        xs[b][j] = stack[((long long)b * NROWS + row) * D_N + j];
    __syncthreads();
    float acc[B_N] = {0.f, 0.f, 0.f, 0.f};
#pragma unroll 8
    for (int d = 0; d < D_N; ++d) {
        float w = W[d * D_N + j];
#pragma unroll
        for (int b = 0; b < B_N; ++b)
            acc[b] += xs[b][d] * w;
    }
    float m = 0.25f * (acc[0] + acc[1] + acc[2] + acc[3]);
#pragma unroll
    for (int b = 0; b < B_N; ++b)
        stack[((long long)b * NROWS + row) * D_N + j] =
            1.0f / (1.0f + __expf(-acc[b]));
    mean_out[(long long)row * D_N + j] = 1.0f / (1.0f + __expf(-m));
}

// ---------------------------------------------------------------------------
extern "C" void kernel_launch(void* const* d_in, const int* in_sizes, int n_in,
                              void* d_out, int out_size, void* d_ws, size_t ws_size,
                              hipStream_t stream) {
    const float* user_emb = (const float*)d_in[0];
    const float* item_emb = (const float*)d_in[1];
    const int*   rows     = (const int*)  d_in[2];
    const int*   cols     = (const int*)  d_in[3];
    const float* vals     = (const float*)d_in[4];
    const float* u_w      = (const float*)d_in[5];
    const float* i_w      = (const float*)d_in[6];

    float* out = (float*)d_out;
    float* user_mean = out;
    float* item_mean = out + (long long)U_N * D_N;
    float* stack_u   = item_mean + (long long)I_N * D_N;     // user_embs out
    float* stack_i   = stack_u + (long long)B_N * U_N * D_N; // item_embs out

    // Workspace (~96 MB): pay(64) | userW16(12.8) | itemW16(6.4) |
    //                     cnt16(12.8, becomes local prefixes) | cnt_ch | off_ch
    uint2* pay = (uint2*)d_ws;
    unsigned short* userW16 = (unsigned short*)(pay + EDGES);   // user_emb @ i_w
    unsigned short* itemW16 = userW16 + (size_t)U_N * D_N;      // item_emb @ u_w
    unsigned short* cnt16 = itemW16 + (size_t)I_N * D_N;
    int* cnt_ch = (int*)(cnt16 + (size_t)NBLK * CROW);
    int* off_ch = cnt_ch + CROW;
    size_t needed = ((char*)(off_ch + CROW)) - (char*)d_ws;

    if (ws_size >= needed) {
        precompW_kernel<<<(I_N + 31) / 32, 256, 0, stream>>>(item_emb, u_w,
                                                             itemW16, I_N);
        precompW_kernel<<<(U_N + 31) / 32, 256, 0, stream>>>(user_emb, i_w,
                                                             userW16, U_N);
        // ---- user side: keys=rows, gathers itemW16 ----
        bhist_kernel<<<NBLK, 1024, 0, stream>>>(rows, cnt16);
        scan_tot<<<(NSC_U + 1023) / 1024, 1024, 0, stream>>>(cnt16, NSC_U, cnt_ch);
        scan_ex<<<1, 1024, 0, stream>>>(cnt_ch, NSC_U, off_ch);
        scan_cur<<<(NSC_U + 1023) / 1024, 1024, 0, stream>>>(cnt16, NSC_U);
        cplace_kernel<<<NBLK, 1024, 0, stream>>>(rows, cols, vals, off_ch, cnt16,
                                                 NSC_U, pay);
        fused_kernel<<<NSC_U, 512, 0, stream>>>(itemW16, off_ch, cnt_ch, pay,
                                                stack_u, user_mean, U_N);
        // ---- item side: keys=cols, gathers userW16 ----
        bhist_kernel<<<NBLK, 1024, 0, stream>>>(cols, cnt16);
        scan_tot<<<(NSC_I + 1023) / 1024, 1024, 0, stream>>>(cnt16, NSC_I, cnt_ch);
        scan_ex<<<1, 1024, 0, stream>>>(cnt_ch, NSC_I, off_ch);
        scan_cur<<<(NSC_I + 1023) / 1024, 1024, 0, stream>>>(cnt16, NSC_I);
        cplace_kernel<<<NBLK, 1024, 0, stream>>>(cols, rows, vals, off_ch, cnt16,
                                                 NSC_I, pay);
        fused_kernel<<<NSC_I, 512, 0, stream>>>(userW16, off_ch, cnt_ch, pay,
                                                stack_i, item_mean, I_N);
    } else {
        size_t stack_bytes = sizeof(float) * (size_t)B_N * (U_N + I_N) * D_N;
        hipMemsetAsync(stack_u, 0, stack_bytes, stream);
        long long nthreads = (long long)EDGES * 16;
        int nblocks = (int)((nthreads + 255) / 256);
        scatter_atomic_kernel<<<nblocks, 256, 0, stream>>>(
            user_emb, item_emb, rows, cols, vals, stack_u, stack_i);
        transform_kernel<U_N><<<U_N, 64, 0, stream>>>(stack_u, u_w, user_mean);
        transform_kernel<I_N><<<I_N, 64, 0, stream>>>(stack_i, i_w, item_mean);
    }
}